// Round 11
// baseline (171.312 us; speedup 1.0000x reference)
//
#include <hip/hip_runtime.h>
#include <math.h>

// ClusterisedSelfAttentionNotLearnable — MFMA R11: persistent W'-resident blocks.
//   out[n,d] = (1/den[n]) * sum_e enc[n,e] * wbar[n,(d,e)]
//   wbar = exp(scores) @ W' : GEMM [N,256]x[256,240pad] bf16 16x16x32
// One 512-thread block per CU. ALL of W' (120 KB, fragment-ordered) resident in
// LDS; staged once with ONE barrier. Block loops over batches of 256 points.
// A-frags are computed DIRECTLY in registers per lane (layout A[m=ln][k=ks*32+q*8+j]
// means lane (q,ln) needs exactly clusters {ks*32+q*8..+8} of point ln) -> no
// A exchange, no staging, ZERO barriers in the steady-state loop. enc/denom live
// in wave-private LDS regions (intra-wave ordering only).

#define NCLUST   256
#define THREADS  512
#define M_BLK    256                     // points per batch (8 waves x 32)
#define NTILES   15
#define BG_BYTES (NTILES * 8 * 64 * 16)  // 122880
#define ENC_STRIDE 152                   // bytes per point-row (72 e x 2B + pad; 32-bank clean)
#define ENC_WAVE  (32 * ENC_STRIDE)      // 4864 per wave

typedef __attribute__((ext_vector_type(8))) short bfrag_t;   // 8 bf16
typedef __attribute__((ext_vector_type(4))) float cfrag_t;   // 4 f32
typedef union { bfrag_t f; unsigned int u[4]; } fragU;

static __device__ __forceinline__ unsigned int f2bf_u(float f) {
    unsigned int u = __float_as_uint(f);
    u += 0x7fffu + ((u >> 16) & 1u);     // RNE
    return u >> 16;
}
static __device__ __forceinline__ unsigned int f2bf2(float lo, float hi) {
    return f2bf_u(lo) | (f2bf_u(hi) << 16);
}
static __device__ __forceinline__ float bf2f(unsigned short s) {
    return __uint_as_float(((unsigned int)s) << 16);
}
static __device__ __forceinline__ void glds16(const void* g, void* l) {
    __builtin_amdgcn_global_load_lds(
        (const __attribute__((address_space(1))) unsigned int*)g,
        (__attribute__((address_space(3))) unsigned int*)l, 16, 0, 0);
}

// Build W' in fragment order (unchanged from R7): unit u -> (tile=u>>9,
// ks=(u>>6)&7, lane=u&63), lane=(q=lane>>4, ln=lane&15);
// holds W'[jp=tile*16+ln][c=ks*32+q*8 .. +8]; jp pad cols (e>=72) are zero.
__global__ void prep_kernel(const float* __restrict__ W, uint4* __restrict__ Bg) {
    const int u = blockIdx.x * 256 + threadIdx.x;
    if (u >= NTILES * 8 * 64) return;
    const int lane = u & 63, ks = (u >> 6) & 7, tile = u >> 9;
    const int ln = lane & 15, q = lane >> 4;
    const int jp = tile * 16 + ln;
    const int d  = jp / 80;
    const int e  = jp - d * 80;
    const int c0 = ks * 32 + q * 8;
    unsigned int w[4] = {0u, 0u, 0u, 0u};
    if (e < 72) {
#pragma unroll
        for (int i = 0; i < 4; ++i) {
            float f0 = W[((c0 + 2 * i)     * 3 + d) * 72 + e];
            float f1 = W[((c0 + 2 * i + 1) * 3 + d) * 72 + e];
            w[i] = f2bf2(f0, f1);
        }
    }
    Bg[u] = make_uint4(w[0], w[1], w[2], w[3]);
}

__global__ __launch_bounds__(THREADS, 2) void rgb_attn_mfma(
    const float* __restrict__ X,
    const float* __restrict__ cent,
    const void* __restrict__ Bg,
    float* __restrict__ out, int N, int nbt)
{
    __shared__ __align__(16) unsigned char Wlds[BG_BYTES];      // 122880
    __shared__ __align__(16) unsigned char encL[8 * ENC_WAVE];  // 38912
    __shared__ __align__(16) float denomL[256];                 // 1024  -> 162816 total

    const int tid  = threadIdx.x;
    const int wv   = tid >> 6;     // wave 0..7
    const int lane = tid & 63;
    const int q    = lane >> 4;
    const int ln   = lane & 15;

    // ---- stage all of W' once (15 x 512 units of 16 B) ----
#pragma unroll
    for (int i = 0; i < 15; ++i) {
        const int u = i * 512 + tid;   // wave-uniform base + lane*16
        glds16((const char*)Bg + u * 16, Wlds + u * 16);
    }

    bool first = true;
    for (int bt = blockIdx.x; bt < nbt; bt += gridDim.x) {
        const int base = bt * M_BLK + wv * 32;   // this wave's 32 points

        // ---- load x for this lane's two points (mt=0,1 -> base+mt*16+ln) ----
        float xx[2][6];
#pragma unroll
        for (int mt = 0; mt < 2; ++mt) {
            int g = base + mt * 16 + ln;
            g = (g < N) ? g : (N - 1);
            const float2 v0 = *(const float2*)(X + g * 6 + 0);
            const float2 v1 = *(const float2*)(X + g * 6 + 2);
            const float2 v2 = *(const float2*)(X + g * 6 + 4);
            xx[mt][0] = v0.x; xx[mt][1] = v0.y;
            xx[mt][2] = v1.x; xx[mt][3] = v1.y;
            xx[mt][4] = v2.x; xx[mt][5] = v2.y;
        }

        // ---- enc (wave-private LDS region, row = mt*16+ln, stride 152) ----
        // q splits the 36 (dim,freq) pairs: dims 3*(q>>1)+k, freqs 3*(q&1)+ff
        {
            unsigned char* wbase = encL + wv * ENC_WAVE;
#pragma unroll
            for (int k = 0; k < 3; ++k) {
                const int dd = 3 * (q >> 1) + k;
#pragma unroll
                for (int ff = 0; ff < 3; ++ff) {
                    const int f  = 3 * (q & 1) + ff;
                    const int es = dd * 12 + f;        // sin col
                    const int ec = es + 6;             // cos col
#pragma unroll
                    for (int mt = 0; mt < 2; ++mt) {
                        float s, c;
                        __sincosf(xx[mt][dd] * (float)(1 << f), &s, &c);
                        unsigned char* rp = wbase + (mt * 16 + ln) * ENC_STRIDE;
                        *(unsigned short*)(rp + es * 2) = (unsigned short)f2bf_u(s);
                        *(unsigned short*)(rp + ec * 2) = (unsigned short)f2bf_u(c);
                    }
                }
            }
        }

        // ---- attention DIRECTLY into afrag registers ----
        // lane (q,ln) mt: point base+mt*16+ln, clusters ks*32+q*8+{0..7}
        bfrag_t afrag[2][8];
        float ds0 = 0.0f, ds1 = 0.0f;
#pragma unroll
        for (int ks = 0; ks < 8; ++ks) {
            fragU fa, fb;
#pragma unroll
            for (int jj = 0; jj < 4; ++jj) {
                const int c = ks * 32 + q * 8 + jj * 2;
                const float c0x = cent[c*3+0], c0y = cent[c*3+1], c0z = cent[c*3+2];
                const float c1x = cent[c*3+3], c1y = cent[c*3+4], c1z = cent[c*3+5];
                float sa = fmaf(xx[0][0], c0x, fmaf(xx[0][1], c0y, xx[0][2] * c0z));
                float sb = fmaf(xx[0][0], c1x, fmaf(xx[0][1], c1y, xx[0][2] * c1z));
                float ea = __expf(sa), eb = __expf(sb);
                ds0 += ea + eb;
                fa.u[jj] = f2bf2(ea, eb);
                sa = fmaf(xx[1][0], c0x, fmaf(xx[1][1], c0y, xx[1][2] * c0z));
                sb = fmaf(xx[1][0], c1x, fmaf(xx[1][1], c1y, xx[1][2] * c1z));
                ea = __expf(sa); eb = __expf(sb);
                ds1 += ea + eb;
                fb.u[jj] = f2bf2(ea, eb);
            }
            afrag[0][ks] = fa.f;
            afrag[1][ks] = fb.f;
        }
        // denominator: reduce over the 4 q-lanes of each (mt,ln) point
        ds0 += __shfl_xor(ds0, 16, 64); ds0 += __shfl_xor(ds0, 32, 64);
        ds1 += __shfl_xor(ds1, 16, 64); ds1 += __shfl_xor(ds1, 32, 64);
        if (q == 0) {
            denomL[wv * 32 + ln]      = ds0;
            denomL[wv * 32 + 16 + ln] = ds1;
        }

        if (first) { __syncthreads(); first = false; }   // W' ready (once)

        // ---- main loop: 15 j-tiles, NO barriers, NO staging ----
        float part[3][2][4] = {};
#pragma unroll
        for (int t = 0; t < NTILES; ++t) {
            cfrag_t a0 = {0.f,0.f,0.f,0.f}, a1 = {0.f,0.f,0.f,0.f};
#pragma unroll
            for (int ks = 0; ks < 8; ++ks) {
                const bfrag_t b = *(const bfrag_t*)
                    (Wlds + ((t * 8 + ks) * 64 + lane) * 16);
                a0 = __builtin_amdgcn_mfma_f32_16x16x32_bf16(afrag[0][ks], b, a0, 0,0,0);
                a1 = __builtin_amdgcn_mfma_f32_16x16x32_bf16(afrag[1][ks], b, a1, 0,0,0);
            }
            const int dblk = t / 5;
            int e = (t % 5) * 16 + ln;
            if (e > 71) e = 71;          // pad cols: C==0 exactly, read any finite enc
            const unsigned char* ep = encL + wv * ENC_WAVE + e * 2;
#pragma unroll
            for (int mt = 0; mt < 2; ++mt)
#pragma unroll
                for (int r = 0; r < 4; ++r) {
                    const unsigned short us = *(const unsigned short*)
                        (ep + (mt * 16 + q * 4 + r) * ENC_STRIDE);
                    part[dblk][mt][r] = fmaf((mt ? a1[r] : a0[r]), bf2f(us),
                                             part[dblk][mt][r]);
                }
        }

        // ---- reduce over the 16 j-lanes, normalize, write ----
#pragma unroll
        for (int mask = 1; mask <= 8; mask <<= 1)
#pragma unroll
            for (int d = 0; d < 3; ++d)
#pragma unroll
                for (int mt = 0; mt < 2; ++mt)
#pragma unroll
                    for (int r = 0; r < 4; ++r)
                        part[d][mt][r] += __shfl_xor(part[d][mt][r], mask, 64);

        if (ln == 0) {
#pragma unroll
            for (int mt = 0; mt < 2; ++mt) {
                const float4 dn = *(const float4*)&denomL[wv * 32 + mt * 16 + q * 4];
#pragma unroll
                for (int r = 0; r < 4; ++r) {
                    const int g = base + mt * 16 + q * 4 + r;
                    if (g < N) {
                        const float inv = 1.0f / ((&dn.x)[r]);
                        out[g*3+0] = part[0][mt][r] * inv;
                        out[g*3+1] = part[1][mt][r] * inv;
                        out[g*3+2] = part[2][mt][r] * inv;
                    }
                }
            }
        }
    }
}

// ---- fallback (correct, slow) if d_ws too small ----
__global__ __launch_bounds__(256) void rgb_attn_fallback(
    const float* __restrict__ X, const float* __restrict__ W,
    const float* __restrict__ cent, float* __restrict__ out, int N)
{
    const int n = blockIdx.x * 256 + threadIdx.x;
    const bool valid = (n < N);
    float x[6];
#pragma unroll
    for (int k = 0; k < 6; ++k) x[k] = valid ? X[n * 6 + k] : 0.0f;
    float enc[72];
#pragma unroll
    for (int d = 0; d < 6; ++d)
#pragma unroll
        for (int f = 0; f < 6; ++f) {
            float s, c;
            __sincosf(x[d] * (float)(1 << f), &s, &c);
            enc[d*12+f] = s; enc[d*12+6+f] = c;
        }
    float acc0 = 0, acc1 = 0, acc2 = 0, denom = 0;
#pragma unroll 1
    for (int c = 0; c < NCLUST; ++c) {
        float s = fmaf(x[0], cent[c*3], fmaf(x[1], cent[c*3+1], x[2]*cent[c*3+2]));
        float ew = __expf(s);
        const float* w = W + c * 216;
        float d0 = 0, d1 = 0, d2 = 0;
#pragma unroll
        for (int e = 0; e < 72; ++e) {
            float ee = enc[e];
            d0 = fmaf(ee, w[e], d0);
            d1 = fmaf(ee, w[72 + e], d1);
            d2 = fmaf(ee, w[144 + e], d2);
        }
        denom += ew;
        acc0 = fmaf(ew, d0, acc0); acc1 = fmaf(ew, d1, acc1); acc2 = fmaf(ew, d2, acc2);
    }
    if (valid) {
        float inv = 1.0f / denom;
        out[n*3+0] = acc0*inv; out[n*3+1] = acc1*inv; out[n*3+2] = acc2*inv;
    }
}

extern "C" void kernel_launch(void* const* d_in, const int* in_sizes, int n_in,
                              void* d_out, int out_size, void* d_ws, size_t ws_size,
                              hipStream_t stream)
{
    const float* X    = (const float*)d_in[0];   // [N, 6]
    const float* W    = (const float*)d_in[1];   // [768, 72]
    const float* cent = (const float*)d_in[2];   // [256, 3]
    float* out = (float*)d_out;                  // [N, 3]
    const int N = in_sizes[0] / 6;

    if (ws_size >= (size_t)BG_BYTES) {
        uint4* Bg = (uint4*)d_ws;
        prep_kernel<<<(NTILES * 8 * 64 + 255) / 256, 256, 0, stream>>>(W, Bg);
        const int nbt = (N + M_BLK - 1) / M_BLK;   // 782
        rgb_attn_mfma<<<256, THREADS, 0, stream>>>(X, cent, (const void*)Bg, out, N, nbt);
    } else {
        rgb_attn_fallback<<<(N + 255) / 256, 256, 0, stream>>>(X, W, cent, out, N);
    }
}